// Round 1
// 276.085 us; speedup vs baseline: 1.0071x; 1.0071x over previous
//
#include <hip/hip_runtime.h>

// out[s, :] = W_tok[x[s], :] + b_tok[:] + W_pos[(S-1)-s, :] + b_pos[:]
// S = 8192, D = 1024 floats (= 256 vec4 chunks), all fp32.
//
// Memory-bound: ~96 MB HBM traffic (32 MB W_tok gather + 32 MB W_pos stream
// + 32 MB out stream) -> ~15 us floor at 6.3 TB/s achievable.
//
// R2 structure notes:
//  - ROWS 8->4: payload drops from 16 to 8 live v4f (64->32 VGPR), and
//    __launch_bounds__(256, 8) pins 8 waves/SIMD (32/CU) so the random
//    W_tok gather latency is hidden by TLP, not just intra-wave ILP.
//  - W_pos loads issued BEFORE the token-id load: their addresses don't
//    depend on x[], so they should be in flight during the x load's latency.
//  - Token ids fetched as one block-uniform int4 -> s_load_dwordx4.
typedef float v4f __attribute__((ext_vector_type(4)));

#define ROWS 4

__global__ void __launch_bounds__(256, 8)
embedding_kernel(const int* __restrict__ x,
                 const v4f* __restrict__ W_tok,
                 const v4f* __restrict__ b_tok,
                 const v4f* __restrict__ W_pos,
                 const v4f* __restrict__ b_pos,
                 v4f* __restrict__ out,
                 int S) {
    const int d = threadIdx.x;                 // vec4 chunk 0..255 within a row
    const int s0 = blockIdx.x * ROWS;

    // x-independent streamed loads first (nontemporal: W_pos is read exactly
    // once per launch -> don't allocate in L2).
    v4f p[ROWS];
#pragma unroll
    for (int r = 0; r < ROWS; ++r)
        p[r] = __builtin_nontemporal_load(
            &W_pos[(size_t)(S - 1 - (s0 + r)) * 256 + d]);

    // 4 token ids in one scalar dwordx4 load (address is block-uniform).
    const int4 t = *reinterpret_cast<const int4*>(x + s0);
    const int tok[ROWS] = {t.x, t.y, t.z, t.w};

    // Random-row gather from the 206 MB table (mostly HBM misses).
    v4f a[ROWS];
#pragma unroll
    for (int r = 0; r < ROWS; ++r)
        a[r] = W_tok[(size_t)tok[r] * 256 + d];

    // Tiny, L2/L3-hot: load biases last so the big loads go out first.
    const v4f bsum = b_tok[d] + b_pos[d];

#pragma unroll
    for (int r = 0; r < ROWS; ++r) {
        v4f o = a[r] + p[r] + bsum;
        // out is write-once -> nontemporal store (no RFO/allocate).
        __builtin_nontemporal_store(o, &out[(size_t)(s0 + r) * 256 + d]);
    }
}

extern "C" void kernel_launch(void* const* d_in, const int* in_sizes, int n_in,
                              void* d_out, int out_size, void* d_ws, size_t ws_size,
                              hipStream_t stream) {
    const int* x     = (const int*)d_in[0];        // [8192] int32
    const v4f* W_tok = (const v4f*)d_in[1];        // [50257, 1024] f32
    const v4f* b_tok = (const v4f*)d_in[2];        // [1024] f32
    const v4f* W_pos = (const v4f*)d_in[3];        // [8192, 1024] f32
    const v4f* b_pos = (const v4f*)d_in[4];        // [1024] f32
    v4f* out = (v4f*)d_out;                        // [8192, 1024] f32

    const int S = in_sizes[0];                     // 8192

    embedding_kernel<<<S / ROWS, 256, 0, stream>>>(
        x, W_tok, b_tok, W_pos, b_pos, out, S);
}

// Round 2
// 269.483 us; speedup vs baseline: 1.0318x; 1.0245x over previous
//
#include <hip/hip_runtime.h>

// out[s, :] = W_tok[x[s], :] + b_tok[:] + W_pos[(S-1)-s, :] + b_pos[:]
// S = 8192, D = 1024 floats (= 256 vec4 chunks), all fp32.
//
// Memory-bound: ~96 MB HBM traffic (32 MB W_tok gather + 32 MB W_pos stream
// + 32 MB out stream) -> ~15 us floor at 6.3 TB/s achievable.
//
// R3 structure notes (vmcnt pipelining):
//  - vmcnt is an IN-ORDER counter. R2 loaded biases LAST, so the first
//    row's add forced s_waitcnt vmcnt(0) -> full drain of all 10 loads
//    before any store. Now biases issue FIRST and rows are consumed in
//    load-completion order, so the compiler can emit partial waits
//    (vmcnt(3), vmcnt(2), ...) and the 4 stores overlap the gather tail.
//  - W_tok gather is nontemporal too: rows are ~92% unique and the table
//    is flushed from L2/L3 by the harness poison fill every iteration --
//    nothing worth allocating for.
//  - ROWS=4 + __launch_bounds__(256, 8): 8 waves/SIMD, 32/CU; 256 KB of
//    wave-loads in flight per CU >> Little's-law requirement.
typedef float v4f __attribute__((ext_vector_type(4)));

#define ROWS 4

__global__ void __launch_bounds__(256, 8)
embedding_kernel(const int* __restrict__ x,
                 const v4f* __restrict__ W_tok,
                 const v4f* __restrict__ b_tok,
                 const v4f* __restrict__ W_pos,
                 const v4f* __restrict__ b_pos,
                 v4f* __restrict__ out,
                 int S) {
    const int d = threadIdx.x;                 // vec4 chunk 0..255 within a row
    const int s0 = blockIdx.x * ROWS;

    // Biases first: L2-hot, return quickly, and keep them early in the
    // vmcnt order so later partial waits don't have to drain them.
    const v4f bt = b_tok[d];
    const v4f bp = b_pos[d];

    // 4 token ids in one scalar dwordx4 load (address is block-uniform,
    // goes through the scalar cache -> lgkmcnt, not vmcnt).
    const int4 t = *reinterpret_cast<const int4*>(x + s0);
    const int tok[ROWS] = {t.x, t.y, t.z, t.w};

    // Streamed + gathered loads, interleaved per row so completion order
    // matches consumption order: p0,a0,p1,a1,...
    v4f p[ROWS], a[ROWS];
#pragma unroll
    for (int r = 0; r < ROWS; ++r) {
        p[r] = __builtin_nontemporal_load(
            &W_pos[(size_t)(S - 1 - (s0 + r)) * 256 + d]);
        a[r] = __builtin_nontemporal_load(
            &W_tok[(size_t)tok[r] * 256 + d]);
    }

    const v4f bsum = bt + bp;

    // Consume rows in the order their loads were issued: row r only needs
    // vmcnt to drain through a[r] -> partial waits, stores overlap loads.
#pragma unroll
    for (int r = 0; r < ROWS; ++r) {
        v4f o = a[r] + p[r] + bsum;
        // out is write-once -> nontemporal store (no allocate).
        __builtin_nontemporal_store(o, &out[(size_t)(s0 + r) * 256 + d]);
    }
}

extern "C" void kernel_launch(void* const* d_in, const int* in_sizes, int n_in,
                              void* d_out, int out_size, void* d_ws, size_t ws_size,
                              hipStream_t stream) {
    const int* x     = (const int*)d_in[0];        // [8192] int32
    const v4f* W_tok = (const v4f*)d_in[1];        // [50257, 1024] f32
    const v4f* b_tok = (const v4f*)d_in[2];        // [1024] f32
    const v4f* W_pos = (const v4f*)d_in[3];        // [8192, 1024] f32
    const v4f* b_pos = (const v4f*)d_in[4];        // [1024] f32
    v4f* out = (v4f*)d_out;                        // [8192, 1024] f32

    const int S = in_sizes[0];                     // 8192

    embedding_kernel<<<S / ROWS, 256, 0, stream>>>(
        x, W_tok, b_tok, W_pos, b_pos, out, S);
}